// Round 2
// baseline (2006.920 us; speedup 1.0000x reference)
//
#include <hip/hip_runtime.h>
#include <hip/hip_bf16.h>
#include <cstdint>
#include <cstddef>

// Problem dims (fixed by reference)
#define T_STEPS 500
#define BATCH   128
#define FDIM    128
#define HDIM    512
#define ODIM    32
#define M_ROWS  (T_STEPS * BATCH)   // 64000

__device__ __forceinline__ float bfbits2f(unsigned short u) {
    union { unsigned int i; float f; } c; c.i = ((unsigned int)u) << 16; return c.f;
}

// ---------------------------------------------------------------------------
// Dtype detect: inspect first 512 16-bit words of x. bf16 N(0,1) data ->
// biased exponent <= ~130 always. fp32 data -> even words are random mantissa
// bits -> ~34% have exponent >= 170. flag=1 means fp32 inputs.
// ---------------------------------------------------------------------------
__global__ void detect_kernel(const unsigned short* __restrict__ xw, int* __restrict__ flag) {
    __shared__ int cnt;
    if (threadIdx.x == 0) cnt = 0;
    __syncthreads();
    unsigned short w = xw[threadIdx.x * 2];        // even words: 0..510
    int e = (w >> 7) & 0xFF;
    if (e >= 170) atomicAdd(&cnt, 1);
    __syncthreads();
    if (threadIdx.x == 0) *flag = (cnt >= 8) ? 1 : 0;
}

// ---------------------------------------------------------------------------
// Prep: WrecT32[hp][h] = W_rec[h][hp] (fp32); WoutT32[h][o] = W_out[o][h];
// bout32 upcast. Source dtype per flag.
// ---------------------------------------------------------------------------
__global__ void prep_kernel(const void* __restrict__ Wrec,
                            const void* __restrict__ Wout,
                            const void* __restrict__ bout,
                            const int* __restrict__ flag,
                            float* __restrict__ WrecT,
                            float* __restrict__ WoutT,
                            float* __restrict__ bout32) {
    const int fp32 = *flag;
    int idx = blockIdx.x * blockDim.x + threadIdx.x;
    if (idx < HDIM * HDIM) {
        int h  = idx / HDIM;
        int hp = idx % HDIM;
        float v = fp32 ? ((const float*)Wrec)[idx]
                       : bfbits2f(((const unsigned short*)Wrec)[idx]);
        WrecT[hp * HDIM + h] = v;
    }
    if (idx < ODIM * HDIM) {
        int o = idx / HDIM;
        int h = idx % HDIM;
        float v = fp32 ? ((const float*)Wout)[idx]
                       : bfbits2f(((const unsigned short*)Wout)[idx]);
        WoutT[h * ODIM + o] = v;
    }
    if (idx < ODIM) {
        bout32[idx] = fp32 ? ((const float*)bout)[idx]
                           : bfbits2f(((const unsigned short*)bout)[idx]);
    }
}

// ---------------------------------------------------------------------------
// i_in GEMM, fp32 vector pipe (exact for either input dtype).
// Block: 256 threads, 8 m-rows x 512 h. Each thread: h = tid and tid+256,
// 8 m-rows -> 16 accumulators. x rows staged in LDS (broadcast reads).
// K accumulated in ascending order, serial per output.
// ---------------------------------------------------------------------------
__global__ __launch_bounds__(256) void iin_gemm(const void* __restrict__ x,
                                                const void* __restrict__ Win,
                                                const int* __restrict__ flag,
                                                float* __restrict__ iin) {
    const int fp32 = *flag;
    const int tid  = threadIdx.x;
    const int m0   = blockIdx.x * 8;

    __shared__ float xs[8][FDIM];   // 4 KB

    // stage 8 x-rows (contiguous 1024 elements), coalesced
    for (int i = tid; i < 8 * FDIM; i += 256) {
        size_t g = (size_t)m0 * FDIM + i;
        xs[0][i] = fp32 ? ((const float*)x)[g]
                        : bfbits2f(((const unsigned short*)x)[g]);
    }
    __syncthreads();

    const int h0 = tid, h1 = tid + 256;
    float acc[8][2];
#pragma unroll
    for (int m = 0; m < 8; ++m) { acc[m][0] = 0.f; acc[m][1] = 0.f; }

    if (fp32) {
        const float* W = (const float*)Win;
        for (int k4 = 0; k4 < FDIM / 4; ++k4) {
            float4 w0 = *(const float4*)(W + (size_t)h0 * FDIM + k4 * 4);
            float4 w1 = *(const float4*)(W + (size_t)h1 * FDIM + k4 * 4);
#pragma unroll
            for (int m = 0; m < 8; ++m) {
                float4 xv = *(const float4*)&xs[m][k4 * 4];
                float a0 = acc[m][0], a1 = acc[m][1];
                a0 += xv.x * w0.x; a0 += xv.y * w0.y; a0 += xv.z * w0.z; a0 += xv.w * w0.w;
                a1 += xv.x * w1.x; a1 += xv.y * w1.y; a1 += xv.z * w1.z; a1 += xv.w * w1.w;
                acc[m][0] = a0; acc[m][1] = a1;
            }
        }
    } else {
        const unsigned short* W = (const unsigned short*)Win;
        for (int k4 = 0; k4 < FDIM / 4; ++k4) {
            ushort4 u0 = *(const ushort4*)(W + (size_t)h0 * FDIM + k4 * 4);
            ushort4 u1 = *(const ushort4*)(W + (size_t)h1 * FDIM + k4 * 4);
            float4 w0 = {bfbits2f(u0.x), bfbits2f(u0.y), bfbits2f(u0.z), bfbits2f(u0.w)};
            float4 w1 = {bfbits2f(u1.x), bfbits2f(u1.y), bfbits2f(u1.z), bfbits2f(u1.w)};
#pragma unroll
            for (int m = 0; m < 8; ++m) {
                float4 xv = *(const float4*)&xs[m][k4 * 4];
                float a0 = acc[m][0], a1 = acc[m][1];
                a0 += xv.x * w0.x; a0 += xv.y * w0.y; a0 += xv.z * w0.z; a0 += xv.w * w0.w;
                a1 += xv.x * w1.x; a1 += xv.y * w1.y; a1 += xv.z * w1.z; a1 += xv.w * w1.w;
                acc[m][0] = a0; acc[m][1] = a1;
            }
        }
    }

#pragma unroll
    for (int m = 0; m < 8; ++m) {
        iin[(size_t)(m0 + m) * HDIM + h0] = acc[m][0];
        iin[(size_t)(m0 + m) * HDIM + h1] = acc[m][1];
    }
}

// ---------------------------------------------------------------------------
// Scan: 128 WGs (one per batch elem), 512 threads (one per neuron).
// Sparse recurrent gather via ballot-built spike list; LIF-AdEx update in
// fp32 matching reference expression order; fused readout + exp filter.
// ---------------------------------------------------------------------------
__global__ __launch_bounds__(512) void scan_kernel(const float* __restrict__ iin,
                                                   const float* __restrict__ WrecT,
                                                   const float* __restrict__ WoutT,
                                                   const float* __restrict__ bout,
                                                   const int* __restrict__ flag,
                                                   void* __restrict__ out) {
    const int b    = blockIdx.x;
    const int h    = threadIdx.x;
    const int lane = h & 63;
    const int wv   = h >> 6;
    const int fp32o = *flag;

    __shared__ unsigned long long wmask[8];
    __shared__ unsigned short slist[HDIM];

    const float kDvC  = 0.1f;             // DT*TAU_MEM_INV
    const float kSyn  = 0.2f;             // DT*TAU_SYN_INV
    const float kAda  = 0.002f;           // DT*TAU_ADA_INV
    const float kFilt = 0.2231435511314f; // DT*TAU_FILTER_INV

    float v = 0.f, cur = 0.f, a = 0.f;
    int   cnt = 0;
    float o_state = 0.f;
    const float bo = (h < ODIM) ? bout[h] : 0.f;

    for (int t = 0; t < T_STEPS; ++t) {
        float ic = iin[((size_t)t * BATCH + b) * HDIM + h];

        // recurrent input from previous step's spikes, ascending h'
        float rec = 0.f;
        {
            int j = 0;
            for (; j + 7 < cnt; j += 8) {
                float w0 = WrecT[(size_t)slist[j    ] * HDIM + h];
                float w1 = WrecT[(size_t)slist[j + 1] * HDIM + h];
                float w2 = WrecT[(size_t)slist[j + 2] * HDIM + h];
                float w3 = WrecT[(size_t)slist[j + 3] * HDIM + h];
                float w4 = WrecT[(size_t)slist[j + 4] * HDIM + h];
                float w5 = WrecT[(size_t)slist[j + 5] * HDIM + h];
                float w6 = WrecT[(size_t)slist[j + 6] * HDIM + h];
                float w7 = WrecT[(size_t)slist[j + 7] * HDIM + h];
                rec += w0; rec += w1; rec += w2; rec += w3;
                rec += w4; rec += w5; rec += w6; rec += w7;
            }
            for (; j < cnt; ++j)
                rec += WrecT[(size_t)slist[j] * HDIM + h];
        }

        // state update, expression order mirrors reference
        float s = (0.0f - v) + 0.5f * expf((v - 1.0f) * 2.0f);
        s = s + cur;
        s = s - a;
        float v_dec = v + kDvC * s;
        float i_dec = cur - kSyn * cur;
        float a_dec = a + kAda * (4.0f * v - a);
        bool  z     = (v_dec - 1.0f) > 0.0f;

        v   = z ? 0.0f : v_dec;
        a   = z ? (a_dec + 0.02f) : a_dec;
        cur = (i_dec + ic) + rec;

        // build new spike list (deterministic ascending order)
        unsigned long long m = __ballot(z);
        if (lane == 0) wmask[wv] = m;
        __syncthreads();   // masks visible; old slist fully consumed

        int total = 0, off = 0;
#pragma unroll
        for (int w = 0; w < 8; ++w) {
            int pc = __popcll(wmask[w]);
            if (w < wv) off += pc;
            total += pc;
        }
        off += __popcll(wmask[wv] & ((1ull << lane) - 1ull));
        if (z) slist[off] = (unsigned short)h;
        cnt = total;
        __syncthreads();   // new list complete

        // fused readout + exponential filter (this step's spikes)
        if (h < ODIM) {
            float y = 0.f;
            for (int jj = 0; jj < cnt; ++jj)
                y += WoutT[(size_t)slist[jj] * ODIM + h];
            y = y + bo;    // reference adds bias after the matmul
            o_state = (t == 0) ? y : (o_state + kFilt * (y - o_state));
            size_t oidx = ((size_t)t * BATCH + b) * ODIM + h;
            if (fp32o) ((float*)out)[oidx] = o_state;
            else ((__hip_bfloat16*)out)[oidx] = __float2bfloat16(o_state);
        }
    }
}

// ---------------------------------------------------------------------------
extern "C" void kernel_launch(void* const* d_in, const int* in_sizes, int n_in,
                              void* d_out, int out_size, void* d_ws, size_t ws_size,
                              hipStream_t stream) {
    // select inputs by unique element count (robust to ordering)
    const void* x = d_in[0]; const void* Win = d_in[1]; const void* Wrec = d_in[2];
    const void* Wout = d_in[3]; const void* bout = d_in[4];
    for (int i = 0; i < n_in; ++i) {
        switch (in_sizes[i]) {
            case 8192000: x    = d_in[i]; break;
            case 65536:   Win  = d_in[i]; break;
            case 262144:  Wrec = d_in[i]; break;
            case 16384:   Wout = d_in[i]; break;
            case 32:      bout = d_in[i]; break;
            default: break;
        }
    }

    // workspace layout (bytes)
    const size_t OFF_FLAG  = 0;                       // 4
    const size_t OFF_BOUT  = 128;                     // 32*4 = 128
    const size_t OFF_WOUTT = 256;                     // 512*32*4 = 65536
    const size_t OFF_WRECT = 65792;                   // 512*512*4 = 1048576
    const size_t OFF_IIN   = 1114368;                 // 64000*512*4 = 131072000
    const size_t REQUIRED  = OFF_IIN + (size_t)M_ROWS * HDIM * 4;  // 132186368
    if (ws_size < REQUIRED) return;  // diagnostic: output stays 0 -> absmax == max|ref|

    char* ws = (char*)d_ws;
    int*   flag   = (int*)(ws + OFF_FLAG);
    float* bout32 = (float*)(ws + OFF_BOUT);
    float* WoutT  = (float*)(ws + OFF_WOUTT);
    float* WrecT  = (float*)(ws + OFF_WRECT);
    float* iin    = (float*)(ws + OFF_IIN);

    hipLaunchKernelGGL(detect_kernel, dim3(1), dim3(256), 0, stream,
                       (const unsigned short*)x, flag);
    hipLaunchKernelGGL(prep_kernel, dim3((HDIM * HDIM + 255) / 256), dim3(256), 0, stream,
                       Wrec, Wout, bout, flag, WrecT, WoutT, bout32);
    hipLaunchKernelGGL(iin_gemm, dim3(M_ROWS / 8), dim3(256), 0, stream,
                       x, Win, flag, iin);
    hipLaunchKernelGGL(scan_kernel, dim3(BATCH), dim3(512), 0, stream,
                       iin, WrecT, WoutT, bout32, flag, (void*)d_out);
}

// Round 3
// 1268.908 us; speedup vs baseline: 1.5816x; 1.5816x over previous
//
#include <hip/hip_runtime.h>
#include <hip/hip_bf16.h>
#include <cstdint>
#include <cstddef>

// Problem dims (fixed by reference)
#define T_STEPS 500
#define BATCH   128
#define FDIM    128
#define HDIM    512
#define ODIM    32
#define M_ROWS  (T_STEPS * BATCH)   // 64000

__device__ __forceinline__ float bfbits2f(unsigned short u) {
    union { unsigned int i; float f; } c; c.i = ((unsigned int)u) << 16; return c.f;
}

// ---------------------------------------------------------------------------
// Dtype detect: inspect first 512 16-bit words of x. bf16 N(0,1) data ->
// biased exponent <= ~130 always. fp32 data -> even words are random mantissa
// bits -> ~34% have exponent >= 170. flag=1 means fp32 inputs.
// ---------------------------------------------------------------------------
__global__ void detect_kernel(const unsigned short* __restrict__ xw, int* __restrict__ flag) {
    __shared__ int cnt;
    if (threadIdx.x == 0) cnt = 0;
    __syncthreads();
    unsigned short w = xw[threadIdx.x * 2];
    int e = (w >> 7) & 0xFF;
    if (e >= 170) atomicAdd(&cnt, 1);
    __syncthreads();
    if (threadIdx.x == 0) *flag = (cnt >= 8) ? 1 : 0;
}

// ---------------------------------------------------------------------------
// Prep (fp32 everywhere downstream):
//   WrecT[hp][h]  = W_rec[h][hp]
//   WoutT[h][o]   = W_out[o][h]
//   WinT[f][h]    = W_in[h][f]
//   bout32 upcast
// ---------------------------------------------------------------------------
__global__ void prep_kernel(const void* __restrict__ Wrec,
                            const void* __restrict__ Wout,
                            const void* __restrict__ bout,
                            const void* __restrict__ Win,
                            const int* __restrict__ flag,
                            float* __restrict__ WrecT,
                            float* __restrict__ WoutT,
                            float* __restrict__ WinT,
                            float* __restrict__ bout32) {
    const int fp32 = *flag;
    int idx = blockIdx.x * blockDim.x + threadIdx.x;
    if (idx < HDIM * HDIM) {
        int h  = idx / HDIM;
        int hp = idx % HDIM;
        float v = fp32 ? ((const float*)Wrec)[idx]
                       : bfbits2f(((const unsigned short*)Wrec)[idx]);
        WrecT[hp * HDIM + h] = v;
    }
    if (idx < ODIM * HDIM) {
        int o = idx / HDIM;
        int h = idx % HDIM;
        float v = fp32 ? ((const float*)Wout)[idx]
                       : bfbits2f(((const unsigned short*)Wout)[idx]);
        WoutT[h * ODIM + o] = v;
    }
    if (idx < HDIM * FDIM) {
        int h = idx / FDIM;
        int f = idx % FDIM;
        float v = fp32 ? ((const float*)Win)[idx]
                       : bfbits2f(((const unsigned short*)Win)[idx]);
        WinT[f * HDIM + h] = v;
    }
    if (idx < ODIM) {
        bout32[idx] = fp32 ? ((const float*)bout)[idx]
                           : bfbits2f(((const unsigned short*)bout)[idx]);
    }
}

// ---------------------------------------------------------------------------
// i_in GEMM v2: coalesced W_in^T loads. Block 256 thr handles 32 m-rows.
// Lane p owns h = tid and h = tid+256: W_T[k][h] loads are consecutive
// across lanes (coalesced). x rows staged in LDS, broadcast reads.
// k accumulated ascending, sequential per output (same order as R2 pass).
// ---------------------------------------------------------------------------
__global__ __launch_bounds__(256) void iin_gemm(const void* __restrict__ x,
                                                const float* __restrict__ WinT,
                                                const int* __restrict__ flag,
                                                float* __restrict__ iin) {
    const int fp32 = *flag;
    const int tid  = threadIdx.x;
    const int m0   = blockIdx.x * 32;

    __shared__ float xs[32][FDIM];   // 16 KB

    for (int i = tid; i < 32 * FDIM; i += 256) {
        size_t g = (size_t)m0 * FDIM + i;
        xs[0][i] = fp32 ? ((const float*)x)[g]
                        : bfbits2f(((const unsigned short*)x)[g]);
    }
    __syncthreads();

    float acc[32][2];
#pragma unroll
    for (int m = 0; m < 32; ++m) { acc[m][0] = 0.f; acc[m][1] = 0.f; }

#pragma unroll 4
    for (int k = 0; k < FDIM; ++k) {
        float w0 = WinT[(size_t)k * HDIM + tid];
        float w1 = WinT[(size_t)k * HDIM + 256 + tid];
#pragma unroll
        for (int m = 0; m < 32; ++m) {
            float xv = xs[m][k];
            acc[m][0] += xv * w0;
            acc[m][1] += xv * w1;
        }
    }

#pragma unroll
    for (int m = 0; m < 32; ++m) {
        iin[(size_t)(m0 + m) * HDIM + tid]       = acc[m][0];
        iin[(size_t)(m0 + m) * HDIM + 256 + tid] = acc[m][1];
    }
}

// ---------------------------------------------------------------------------
// Scan v2: 128 WGs (one per batch elem), 512 threads (one per neuron).
// Per step: state update + ballot FIRST (independent of recurrent input),
// then software-pipelined sparse gather over the previous spike list
// (double-buffered 8-groups; strictly ascending add order), double-buffered
// slist, spike masks written to global for the offloaded readout.
// ---------------------------------------------------------------------------
__global__ __launch_bounds__(512) void scan_kernel(const float* __restrict__ iin,
                                                   const float* __restrict__ WrecT,
                                                   unsigned long long* __restrict__ masksG) {
    const int b    = blockIdx.x;
    const int h    = threadIdx.x;
    const int lane = h & 63;
    const int wv   = h >> 6;

    __shared__ unsigned long long wmask[8];
    __shared__ unsigned short slA[HDIM], slB[HDIM];
    unsigned short* slO = slA;   // list being read (prev step's spikes)
    unsigned short* slN = slB;   // list being built (this step's spikes)

    const float kDvC  = 0.1f;    // DT*TAU_MEM_INV
    const float kSyn  = 0.2f;    // DT*TAU_SYN_INV
    const float kAda  = 0.002f;  // DT*TAU_ADA_INV

    float v = 0.f, cur = 0.f, a = 0.f;
    int   cnt = 0;
    const float* Wc = WrecT + h;   // column base, row stride HDIM

    for (int t = 0; t < T_STEPS; ++t) {
        float ic = iin[((size_t)t * BATCH + b) * HDIM + h];

        // ---- state update from carried state (independent of gather) ----
        float s = (0.0f - v) + 0.5f * expf((v - 1.0f) * 2.0f);
        s = s + cur;
        s = s - a;
        float v_dec = v + kDvC * s;
        float i_dec = cur - kSyn * cur;
        float a_dec = a + kAda * (4.0f * v - a);
        bool  z     = (v_dec - 1.0f) > 0.0f;

        unsigned long long m = __ballot(z);
        if (lane == 0) {
            wmask[wv] = m;
            masksG[((size_t)t * BATCH + b) * 8 + wv] = m;
        }

        v = z ? 0.0f : v_dec;
        a = z ? (a_dec + 0.02f) : a_dec;

        // ---- pipelined gather over PREVIOUS spikes (ascending h') ----
        float rec = 0.f;
        {
            const int ng = cnt >> 3;
            float g0[8], g1[8];
            auto load8 = [&](int base, float* d) {
#pragma unroll
                for (int u = 0; u < 8; ++u)
                    d[u] = Wc[(size_t)slO[base + u] * HDIM];
            };
            int g = 0;
            if (ng > 0) load8(0, g0);
            while (g + 2 <= ng) {
                load8((g + 1) * 8, g1);
#pragma unroll
                for (int u = 0; u < 8; ++u) rec += g0[u];
                if (g + 2 < ng) load8((g + 2) * 8, g0);
#pragma unroll
                for (int u = 0; u < 8; ++u) rec += g1[u];
                g += 2;
            }
            if (g < ng) {
#pragma unroll
                for (int u = 0; u < 8; ++u) rec += g0[u];
            }
            for (int j = ng * 8; j < cnt; ++j)
                rec += Wc[(size_t)slO[j] * HDIM];
        }

        cur = (i_dec + ic) + rec;

        __syncthreads();   // S1: wmask visible; all gathers on slO done

        int total = 0, off = 0;
#pragma unroll
        for (int w = 0; w < 8; ++w) {
            int pc = __popcll(wmask[w]);
            if (w < wv) off += pc;
            total += pc;
        }
        off += __popcll(m & ((1ull << lane) - 1ull));
        if (z) slN[off] = (unsigned short)h;
        cnt = total;

        __syncthreads();   // S2: slN complete before next step reads it

        unsigned short* tmp = slO; slO = slN; slN = tmp;
    }
}

// ---------------------------------------------------------------------------
// Readout from spike masks: y[t][b][o] = sum_{h' spiking} WoutT[h'][o] + b[o]
// Same ascending-h' add order as the R2 in-scan readout. 8 (t,b) pairs per
// 256-thread block; massively parallel (8000 blocks).
// ---------------------------------------------------------------------------
__global__ __launch_bounds__(256) void y_kernel(const unsigned long long* __restrict__ masks,
                                                const float* __restrict__ WoutT,
                                                const float* __restrict__ bout,
                                                float* __restrict__ y) {
    const int tid = threadIdx.x;
    const int p   = blockIdx.x * 8 + (tid >> 5);   // t*BATCH + b
    const int o   = tid & 31;
    const unsigned long long* mp = masks + (size_t)p * 8;
    float acc = 0.f;
#pragma unroll
    for (int w = 0; w < 8; ++w) {
        unsigned long long m = mp[w];
        const float* Wb = WoutT + (size_t)w * 64 * ODIM + o;
        while (m) {
            int j = __builtin_ctzll(m);
            acc += Wb[j * ODIM];
            m &= m - 1;
        }
    }
    y[(size_t)p * ODIM + o] = acc + bout[o];
}

// ---------------------------------------------------------------------------
// Exponential filter over t: 4096 independent (b,o) chains, prefetched.
// ---------------------------------------------------------------------------
__global__ __launch_bounds__(256) void filter_kernel(const float* __restrict__ y,
                                                     const int* __restrict__ flag,
                                                     void* __restrict__ out) {
    const int p = blockIdx.x * 256 + threadIdx.x;   // b*ODIM + o
    const int fp32o = *flag;
    const float kf = 0.2231435511314f;   // DT*TAU_FILTER_INV
    float ycur = y[p];
    float o_state = ycur;
    for (int t = 0; t < T_STEPS; ++t) {
        float ynext = (t + 1 < T_STEPS) ? y[(size_t)(t + 1) * (BATCH * ODIM) + p] : 0.f;
        if (t > 0) o_state = o_state + kf * (ycur - o_state);
        size_t oi = (size_t)t * (BATCH * ODIM) + p;
        if (fp32o) ((float*)out)[oi] = o_state;
        else       ((__hip_bfloat16*)out)[oi] = __float2bfloat16(o_state);
        ycur = ynext;
    }
}

// ---------------------------------------------------------------------------
extern "C" void kernel_launch(void* const* d_in, const int* in_sizes, int n_in,
                              void* d_out, int out_size, void* d_ws, size_t ws_size,
                              hipStream_t stream) {
    // select inputs by unique element count (robust to ordering)
    const void* x = d_in[0]; const void* Win = d_in[1]; const void* Wrec = d_in[2];
    const void* Wout = d_in[3]; const void* bout = d_in[4];
    for (int i = 0; i < n_in; ++i) {
        switch (in_sizes[i]) {
            case 8192000: x    = d_in[i]; break;
            case 65536:   Win  = d_in[i]; break;
            case 262144:  Wrec = d_in[i]; break;
            case 16384:   Wout = d_in[i]; break;
            case 32:      bout = d_in[i]; break;
            default: break;
        }
    }

    // workspace layout (bytes)
    const size_t OFF_FLAG  = 0;          // 4
    const size_t OFF_BOUT  = 256;        // 128
    const size_t OFF_WOUTT = 512;        // 65536
    const size_t OFF_WRECT = 66048;      // 1048576
    const size_t OFF_WINT  = 1114624;    // 262144
    const size_t OFF_MASK  = 1376768;    // 500*128*8*8 = 4096000
    const size_t OFF_IIN   = 5472768;    // 64000*512*4 = 131072000
    const size_t OFF_Y     = OFF_IIN;    // y (8.2 MB) aliases iin (dead after scan)
    const size_t REQUIRED  = OFF_IIN + (size_t)M_ROWS * HDIM * 4;  // 136544768
    if (ws_size < REQUIRED) return;  // diagnostic: output stays 0

    char* ws = (char*)d_ws;
    int*    flag   = (int*)(ws + OFF_FLAG);
    float*  bout32 = (float*)(ws + OFF_BOUT);
    float*  WoutT  = (float*)(ws + OFF_WOUTT);
    float*  WrecT  = (float*)(ws + OFF_WRECT);
    float*  WinT   = (float*)(ws + OFF_WINT);
    unsigned long long* masks = (unsigned long long*)(ws + OFF_MASK);
    float*  iin    = (float*)(ws + OFF_IIN);
    float*  y      = (float*)(ws + OFF_Y);

    hipLaunchKernelGGL(detect_kernel, dim3(1), dim3(256), 0, stream,
                       (const unsigned short*)x, flag);
    hipLaunchKernelGGL(prep_kernel, dim3((HDIM * HDIM + 255) / 256), dim3(256), 0, stream,
                       Wrec, Wout, bout, Win, flag, WrecT, WoutT, WinT, bout32);
    hipLaunchKernelGGL(iin_gemm, dim3(M_ROWS / 32), dim3(256), 0, stream,
                       x, WinT, flag, iin);
    hipLaunchKernelGGL(scan_kernel, dim3(BATCH), dim3(512), 0, stream,
                       iin, WrecT, masks);
    hipLaunchKernelGGL(y_kernel, dim3(M_ROWS / 8), dim3(256), 0, stream,
                       masks, WoutT, bout32, y);
    hipLaunchKernelGGL(filter_kernel, dim3((BATCH * ODIM) / 256), dim3(256), 0, stream,
                       y, flag, d_out);
}

// Round 4
// 995.433 us; speedup vs baseline: 2.0161x; 1.2747x over previous
//
#include <hip/hip_runtime.h>
#include <hip/hip_bf16.h>
#include <cstdint>
#include <cstddef>

// Problem dims (fixed by reference)
#define T_STEPS 500
#define BATCH   128
#define FDIM    128
#define HDIM    512
#define ODIM    32
#define M_ROWS  (T_STEPS * BATCH)   // 64000
#define ZOFF    (512u << 11)        // byte offset of the zero row in WrecT

__device__ __forceinline__ float bfbits2f(unsigned short u) {
    union { unsigned int i; float f; } c; c.i = ((unsigned int)u) << 16; return c.f;
}

// ---------------------------------------------------------------------------
// Dtype detect: inspect first 512 16-bit words of x. bf16 N(0,1) data ->
// biased exponent <= ~130 always. fp32 data -> even words are random mantissa
// bits -> ~34% have exponent >= 170. flag=1 means fp32 inputs.
// ---------------------------------------------------------------------------
__global__ void detect_kernel(const unsigned short* __restrict__ xw, int* __restrict__ flag) {
    __shared__ int cnt;
    if (threadIdx.x == 0) cnt = 0;
    __syncthreads();
    unsigned short w = xw[threadIdx.x * 2];
    int e = (w >> 7) & 0xFF;
    if (e >= 170) atomicAdd(&cnt, 1);
    __syncthreads();
    if (threadIdx.x == 0) *flag = (cnt >= 8) ? 1 : 0;
}

// ---------------------------------------------------------------------------
// Prep (fp32 everywhere downstream):
//   WrecT[hp][h]  = W_rec[h][hp], plus zero row at hp = 512 (gather padding)
//   WoutT[h][o]   = W_out[o][h]
//   WinT[f][h]    = W_in[h][f]
//   bout32 upcast
// ---------------------------------------------------------------------------
__global__ void prep_kernel(const void* __restrict__ Wrec,
                            const void* __restrict__ Wout,
                            const void* __restrict__ bout,
                            const void* __restrict__ Win,
                            const int* __restrict__ flag,
                            float* __restrict__ WrecT,
                            float* __restrict__ WoutT,
                            float* __restrict__ WinT,
                            float* __restrict__ bout32) {
    const int fp32 = *flag;
    int idx = blockIdx.x * blockDim.x + threadIdx.x;
    if (idx < HDIM * HDIM) {
        int h  = idx / HDIM;
        int hp = idx % HDIM;
        float v = fp32 ? ((const float*)Wrec)[idx]
                       : bfbits2f(((const unsigned short*)Wrec)[idx]);
        WrecT[hp * HDIM + h] = v;
    }
    if (idx < HDIM) WrecT[HDIM * HDIM + idx] = 0.f;   // zero pad row
    if (idx < ODIM * HDIM) {
        int o = idx / HDIM;
        int h = idx % HDIM;
        float v = fp32 ? ((const float*)Wout)[idx]
                       : bfbits2f(((const unsigned short*)Wout)[idx]);
        WoutT[h * ODIM + o] = v;
    }
    if (idx < HDIM * FDIM) {
        int h = idx / FDIM;
        int f = idx % FDIM;
        float v = fp32 ? ((const float*)Win)[idx]
                       : bfbits2f(((const unsigned short*)Win)[idx]);
        WinT[f * HDIM + h] = v;
    }
    if (idx < ODIM) {
        bout32[idx] = fp32 ? ((const float*)bout)[idx]
                           : bfbits2f(((const unsigned short*)bout)[idx]);
    }
}

// ---------------------------------------------------------------------------
// i_in GEMM (unchanged from R3 — known good): coalesced W_in^T loads.
// ---------------------------------------------------------------------------
__global__ __launch_bounds__(256) void iin_gemm(const void* __restrict__ x,
                                                const float* __restrict__ WinT,
                                                const int* __restrict__ flag,
                                                float* __restrict__ iin) {
    const int fp32 = *flag;
    const int tid  = threadIdx.x;
    const int m0   = blockIdx.x * 32;

    __shared__ float xs[32][FDIM];   // 16 KB

    for (int i = tid; i < 32 * FDIM; i += 256) {
        size_t g = (size_t)m0 * FDIM + i;
        xs[0][i] = fp32 ? ((const float*)x)[g]
                        : bfbits2f(((const unsigned short*)x)[g]);
    }
    __syncthreads();

    float acc[32][2];
#pragma unroll
    for (int m = 0; m < 32; ++m) { acc[m][0] = 0.f; acc[m][1] = 0.f; }

#pragma unroll 4
    for (int k = 0; k < FDIM; ++k) {
        float w0 = WinT[(size_t)k * HDIM + tid];
        float w1 = WinT[(size_t)k * HDIM + 256 + tid];
#pragma unroll
        for (int m = 0; m < 32; ++m) {
            float xv = xs[m][k];
            acc[m][0] += xv * w0;
            acc[m][1] += xv * w1;
        }
    }

#pragma unroll
    for (int m = 0; m < 32; ++m) {
        iin[(size_t)(m0 + m) * HDIM + tid]       = acc[m][0];
        iin[(size_t)(m0 + m) * HDIM + 256 + tid] = acc[m][1];
    }
}

// ---------------------------------------------------------------------------
// Scan v3: 128 WGs (one per batch elem), 1024 threads = 2 per neuron.
// Thread (h, p): p=0 sums even-position spikes, p=1 odd positions; partials
// combined via LDS (rec = part0 + part1, identical on both copies; both
// maintain redundant state). Spike lists are parity-separated uint32 BYTE
// offsets (h'<<11), padded to x16 with a zero-row offset -> uniform
// double-buffered 16-groups, ds_read_b128 index loads, no tail code.
// ---------------------------------------------------------------------------
__global__ __launch_bounds__(1024) void scan_kernel(const float* __restrict__ iin,
                                                    const float* __restrict__ WrecT,
                                                    unsigned long long* __restrict__ masksG) {
    const int b    = blockIdx.x;
    const int tid  = threadIdx.x;
    const int h    = tid & (HDIM - 1);
    const int p    = tid >> 9;          // 0 or 1
    const int lane = tid & 63;
    const int wv   = tid >> 6;          // 0..15; waves 0-7 are p=0

    __shared__ unsigned long long wmask[8];
    __shared__ float part[2][HDIM];                       // 4 KB
    __shared__ alignas(16) unsigned int slAe[288], slAo[288];
    __shared__ alignas(16) unsigned int slBe[288], slBo[288];
    unsigned int *slOe = slAe, *slOo = slAo;   // read lists (prev spikes)
    unsigned int *slNe = slBe, *slNo = slBo;   // build lists (this step)

    const float kDvC  = 0.1f;    // DT*TAU_MEM_INV
    const float kSyn  = 0.2f;    // DT*TAU_SYN_INV
    const float kAda  = 0.002f;  // DT*TAU_ADA_INV

    float v = 0.f, cur = 0.f, a = 0.f;
    int   cnt = 0;
    const char* WB = (const char*)(WrecT + h);

    for (int t = 0; t < T_STEPS; ++t) {
        float ic = iin[((size_t)t * BATCH + b) * HDIM + h];

        // ---- state update from carried state (independent of gather) ----
        float s = (0.0f - v) + 0.5f * expf((v - 1.0f) * 2.0f);
        s = s + cur;
        s = s - a;
        float v_dec = v + kDvC * s;
        float i_dec = cur - kSyn * cur;
        float a_dec = a + kAda * (4.0f * v - a);
        bool  zk    = (v_dec - 1.0f) > 0.0f;

        unsigned long long m = __ballot(zk);
        if (lane == 0 && wv < 8) {
            wmask[wv] = m;
            masksG[((size_t)t * BATCH + b) * 8 + wv] = m;
        }

        v = zk ? 0.0f : v_dec;
        a = zk ? (a_dec + 0.02f) : a_dec;

        // ---- pipelined gather over my parity class of PREVIOUS spikes ----
        float rsum = 0.f;
        {
            const unsigned int* sl = p ? slOo : slOe;
            const int n  = p ? (cnt >> 1) : ((cnt + 1) >> 1);
            const int ng = (n + 15) >> 4;        // padded groups of 16
            float b0[16], b1[16];
            auto ld16 = [&](int g, float* d) {
                const uint4* q = (const uint4*)(sl + (g << 4));
                uint4 i0 = q[0], i1 = q[1], i2 = q[2], i3 = q[3];
                d[0]  = *(const float*)(WB + i0.x);
                d[1]  = *(const float*)(WB + i0.y);
                d[2]  = *(const float*)(WB + i0.z);
                d[3]  = *(const float*)(WB + i0.w);
                d[4]  = *(const float*)(WB + i1.x);
                d[5]  = *(const float*)(WB + i1.y);
                d[6]  = *(const float*)(WB + i1.z);
                d[7]  = *(const float*)(WB + i1.w);
                d[8]  = *(const float*)(WB + i2.x);
                d[9]  = *(const float*)(WB + i2.y);
                d[10] = *(const float*)(WB + i2.z);
                d[11] = *(const float*)(WB + i2.w);
                d[12] = *(const float*)(WB + i3.x);
                d[13] = *(const float*)(WB + i3.y);
                d[14] = *(const float*)(WB + i3.z);
                d[15] = *(const float*)(WB + i3.w);
            };
            int g = 0;
            if (ng > 0) ld16(0, b0);
            while (g + 2 <= ng) {
                ld16(g + 1, b1);
#pragma unroll
                for (int u = 0; u < 16; ++u) rsum += b0[u];
                if (g + 2 < ng) ld16(g + 2, b0);
#pragma unroll
                for (int u = 0; u < 16; ++u) rsum += b1[u];
                g += 2;
            }
            if (g < ng) {
#pragma unroll
                for (int u = 0; u < 16; ++u) rsum += b0[u];
            }
        }
        part[p][h] = rsum;

        __syncthreads();   // B1: wmask + partials visible; slO fully consumed

        float rec = part[0][h] + part[1][h];   // identical on both copies
        cur = (i_dec + ic) + rec;

        // ---- prefix over wmask; build parity-separated new lists ----
        int total = 0, off = 0;
        const int wv7 = wv & 7;
#pragma unroll
        for (int w = 0; w < 8; ++w) {
            int pc = __popcll(wmask[w]);
            if (w < wv7) off += pc;
            total += pc;
        }
        off += __popcll(m & ((1ull << lane) - 1ull));
        if (zk && p == 0) {
            unsigned int hoff = (unsigned int)h << 11;
            if (off & 1) slNo[off >> 1] = hoff;
            else         slNe[off >> 1] = hoff;
        }
        // zero-row padding to x16 per list
        {
            int ne = (total + 1) >> 1, no = total >> 1;
            int neP = (ne + 15) & ~15, noP = (no + 15) & ~15;
            if (tid < neP - ne) slNe[ne + tid] = ZOFF;
            if (tid < noP - no) slNo[no + tid] = ZOFF;
        }
        cnt = total;

        __syncthreads();   // B2: new lists complete before next step reads

        unsigned int* tp;
        tp = slOe; slOe = slNe; slNe = tp;
        tp = slOo; slOo = slNo; slNo = tp;
    }
}

// ---------------------------------------------------------------------------
// Readout from spike masks: y[t][b][o] = sum_{h' spiking} WoutT[h'][o] + b[o]
// ---------------------------------------------------------------------------
__global__ __launch_bounds__(256) void y_kernel(const unsigned long long* __restrict__ masks,
                                                const float* __restrict__ WoutT,
                                                const float* __restrict__ bout,
                                                float* __restrict__ y) {
    const int tid = threadIdx.x;
    const int p   = blockIdx.x * 8 + (tid >> 5);   // t*BATCH + b
    const int o   = tid & 31;
    const unsigned long long* mp = masks + (size_t)p * 8;
    float acc = 0.f;
#pragma unroll
    for (int w = 0; w < 8; ++w) {
        unsigned long long m = mp[w];
        const float* Wb = WoutT + (size_t)w * 64 * ODIM + o;
        while (m) {
            int j = __builtin_ctzll(m);
            acc += Wb[j * ODIM];
            m &= m - 1;
        }
    }
    y[(size_t)p * ODIM + o] = acc + bout[o];
}

// ---------------------------------------------------------------------------
// Exponential filter over t: 4096 independent (b,o) chains; 10-deep chunked
// prefetch hides L2 latency; 64-thread blocks spread over 64 CUs.
// ---------------------------------------------------------------------------
__global__ __launch_bounds__(64) void filter_kernel(const float* __restrict__ y,
                                                    const int* __restrict__ flag,
                                                    void* __restrict__ out) {
    const int p = blockIdx.x * 64 + threadIdx.x;   // b*ODIM + o
    const int fp32o = *flag;
    const float kf = 0.2231435511314f;   // DT*TAU_FILTER_INV
    float c0[10], c1[10];
#pragma unroll
    for (int u = 0; u < 10; ++u) c0[u] = y[(size_t)u * (BATCH * ODIM) + p];
    float o_state = 0.f;
    for (int base = 0; base < T_STEPS; base += 10) {
        if (base + 10 < T_STEPS) {
#pragma unroll
            for (int u = 0; u < 10; ++u)
                c1[u] = y[(size_t)(base + 10 + u) * (BATCH * ODIM) + p];
        }
#pragma unroll
        for (int u = 0; u < 10; ++u) {
            int t = base + u;
            float yt = c0[u];
            o_state = (t == 0) ? yt : (o_state + kf * (yt - o_state));
            size_t oi = (size_t)t * (BATCH * ODIM) + p;
            if (fp32o) ((float*)out)[oi] = o_state;
            else       ((__hip_bfloat16*)out)[oi] = __float2bfloat16(o_state);
        }
#pragma unroll
        for (int u = 0; u < 10; ++u) c0[u] = c1[u];
    }
}

// ---------------------------------------------------------------------------
extern "C" void kernel_launch(void* const* d_in, const int* in_sizes, int n_in,
                              void* d_out, int out_size, void* d_ws, size_t ws_size,
                              hipStream_t stream) {
    // select inputs by unique element count (robust to ordering)
    const void* x = d_in[0]; const void* Win = d_in[1]; const void* Wrec = d_in[2];
    const void* Wout = d_in[3]; const void* bout = d_in[4];
    for (int i = 0; i < n_in; ++i) {
        switch (in_sizes[i]) {
            case 8192000: x    = d_in[i]; break;
            case 65536:   Win  = d_in[i]; break;
            case 262144:  Wrec = d_in[i]; break;
            case 16384:   Wout = d_in[i]; break;
            case 32:      bout = d_in[i]; break;
            default: break;
        }
    }

    // workspace layout (bytes)
    const size_t OFF_FLAG  = 0;          // 4
    const size_t OFF_BOUT  = 256;        // 128
    const size_t OFF_WOUTT = 512;        // 65536
    const size_t OFF_WRECT = 66048;      // 513*512*4 = 1050624 (zero pad row)
    const size_t OFF_WINT  = 1116672;    // 262144
    const size_t OFF_MASK  = 1378816;    // 500*128*8*8 = 4096000
    const size_t OFF_IIN   = 5474816;    // 64000*512*4 = 131072000
    const size_t OFF_Y     = OFF_IIN;    // y (8.2 MB) aliases iin (dead after scan)
    const size_t REQUIRED  = OFF_IIN + (size_t)M_ROWS * HDIM * 4;  // 136546816
    if (ws_size < REQUIRED) return;  // diagnostic: output stays 0

    char* ws = (char*)d_ws;
    int*    flag   = (int*)(ws + OFF_FLAG);
    float*  bout32 = (float*)(ws + OFF_BOUT);
    float*  WoutT  = (float*)(ws + OFF_WOUTT);
    float*  WrecT  = (float*)(ws + OFF_WRECT);
    float*  WinT   = (float*)(ws + OFF_WINT);
    unsigned long long* masks = (unsigned long long*)(ws + OFF_MASK);
    float*  iin    = (float*)(ws + OFF_IIN);
    float*  y      = (float*)(ws + OFF_Y);

    hipLaunchKernelGGL(detect_kernel, dim3(1), dim3(256), 0, stream,
                       (const unsigned short*)x, flag);
    hipLaunchKernelGGL(prep_kernel, dim3((HDIM * HDIM + 255) / 256), dim3(256), 0, stream,
                       Wrec, Wout, bout, Win, flag, WrecT, WoutT, WinT, bout32);
    hipLaunchKernelGGL(iin_gemm, dim3(M_ROWS / 32), dim3(256), 0, stream,
                       x, WinT, flag, iin);
    hipLaunchKernelGGL(scan_kernel, dim3(BATCH), dim3(1024), 0, stream,
                       iin, WrecT, masks);
    hipLaunchKernelGGL(y_kernel, dim3(M_ROWS / 8), dim3(256), 0, stream,
                       masks, WoutT, bout32, y);
    hipLaunchKernelGGL(filter_kernel, dim3((BATCH * ODIM) / 64), dim3(64), 0, stream,
                       y, flag, d_out);
}

// Round 5
// 906.813 us; speedup vs baseline: 2.2132x; 1.0977x over previous
//
#include <hip/hip_runtime.h>
#include <hip/hip_bf16.h>
#include <cstdint>
#include <cstddef>

// Problem dims (fixed by reference)
#define T_STEPS 500
#define BATCH   128
#define FDIM    128
#define HDIM    512
#define ODIM    32
#define M_ROWS  (T_STEPS * BATCH)   // 64000
#define ZOFF    (512u << 11)        // byte offset of the zero row in WrecT

__device__ __forceinline__ float bfbits2f(unsigned short u) {
    union { unsigned int i; float f; } c; c.i = ((unsigned int)u) << 16; return c.f;
}

// ---------------------------------------------------------------------------
// Dtype detect: inspect first 512 16-bit words of x. bf16 N(0,1) data ->
// biased exponent <= ~130 always. fp32 data -> even words are random mantissa
// bits -> ~34% have exponent >= 170. flag=1 means fp32 inputs.
// ---------------------------------------------------------------------------
__global__ void detect_kernel(const unsigned short* __restrict__ xw, int* __restrict__ flag) {
    __shared__ int cnt;
    if (threadIdx.x == 0) cnt = 0;
    __syncthreads();
    unsigned short w = xw[threadIdx.x * 2];
    int e = (w >> 7) & 0xFF;
    if (e >= 170) atomicAdd(&cnt, 1);
    __syncthreads();
    if (threadIdx.x == 0) *flag = (cnt >= 8) ? 1 : 0;
}

// ---------------------------------------------------------------------------
// Prep (fp32 everywhere downstream):
//   WrecT[hp][h]  = W_rec[h][hp], plus zero row at hp = 512 (gather padding)
//   WoutT[h][o]   = W_out[o][h]
//   WinT[f][h]    = W_in[h][f]
//   bout32 upcast
// ---------------------------------------------------------------------------
__global__ void prep_kernel(const void* __restrict__ Wrec,
                            const void* __restrict__ Wout,
                            const void* __restrict__ bout,
                            const void* __restrict__ Win,
                            const int* __restrict__ flag,
                            float* __restrict__ WrecT,
                            float* __restrict__ WoutT,
                            float* __restrict__ WinT,
                            float* __restrict__ bout32) {
    const int fp32 = *flag;
    int idx = blockIdx.x * blockDim.x + threadIdx.x;
    if (idx < HDIM * HDIM) {
        int h  = idx / HDIM;
        int hp = idx % HDIM;
        float v = fp32 ? ((const float*)Wrec)[idx]
                       : bfbits2f(((const unsigned short*)Wrec)[idx]);
        WrecT[hp * HDIM + h] = v;
    }
    if (idx < HDIM) WrecT[HDIM * HDIM + idx] = 0.f;   // zero pad row
    if (idx < ODIM * HDIM) {
        int o = idx / HDIM;
        int h = idx % HDIM;
        float v = fp32 ? ((const float*)Wout)[idx]
                       : bfbits2f(((const unsigned short*)Wout)[idx]);
        WoutT[h * ODIM + o] = v;
    }
    if (idx < HDIM * FDIM) {
        int h = idx / FDIM;
        int f = idx % FDIM;
        float v = fp32 ? ((const float*)Win)[idx]
                       : bfbits2f(((const unsigned short*)Win)[idx]);
        WinT[f * HDIM + h] = v;
    }
    if (idx < ODIM) {
        bout32[idx] = fp32 ? ((const float*)bout)[idx]
                           : bfbits2f(((const unsigned short*)bout)[idx]);
    }
}

// ---------------------------------------------------------------------------
// i_in GEMM (unchanged — known good): coalesced W_in^T loads.
// ---------------------------------------------------------------------------
__global__ __launch_bounds__(256) void iin_gemm(const void* __restrict__ x,
                                                const float* __restrict__ WinT,
                                                const int* __restrict__ flag,
                                                float* __restrict__ iin) {
    const int fp32 = *flag;
    const int tid  = threadIdx.x;
    const int m0   = blockIdx.x * 32;

    __shared__ float xs[32][FDIM];   // 16 KB

    for (int i = tid; i < 32 * FDIM; i += 256) {
        size_t g = (size_t)m0 * FDIM + i;
        xs[0][i] = fp32 ? ((const float*)x)[g]
                        : bfbits2f(((const unsigned short*)x)[g]);
    }
    __syncthreads();

    float acc[32][2];
#pragma unroll
    for (int m = 0; m < 32; ++m) { acc[m][0] = 0.f; acc[m][1] = 0.f; }

#pragma unroll 4
    for (int k = 0; k < FDIM; ++k) {
        float w0 = WinT[(size_t)k * HDIM + tid];
        float w1 = WinT[(size_t)k * HDIM + 256 + tid];
#pragma unroll
        for (int m = 0; m < 32; ++m) {
            float xv = xs[m][k];
            acc[m][0] += xv * w0;
            acc[m][1] += xv * w1;
        }
    }

#pragma unroll
    for (int m = 0; m < 32; ++m) {
        iin[(size_t)(m0 + m) * HDIM + tid]       = acc[m][0];
        iin[(size_t)(m0 + m) * HDIM + 256 + tid] = acc[m][1];
    }
}

// ---------------------------------------------------------------------------
// Scan v4: 128 WGs (one per batch elem), 1024 threads.
// Roles: waves 0-7 (tid<512) own neuron h=tid (state + ballot). ALL 16 waves
// gather: thread = (q = tid&127 -> h-quad 4q..4q+3, p = tid>>7 -> one of 8
// parity classes of the spike list). Per spike: ONE global_load_dwordx4
// (16B/lane, 1KB/wave coalesced) covering 4 neurons. Spike lists are 8
// parity-separated uint32 byte-offset sub-lists (hp<<11), each padded to x4
// with the zero-row offset -> ds_read_b128 index loads (broadcast, no
// conflicts), no tail code. Partials part[8][128] (float4) reduced
// ascending-p per neuron. Waves 8-15 start gathering while waves 0-7 do the
// state update -> free overlap. 2 barriers/step.
// ---------------------------------------------------------------------------
__global__ __launch_bounds__(1024) void scan_kernel(const float* __restrict__ iin,
                                                    const float* __restrict__ WrecT,
                                                    unsigned long long* __restrict__ masksG) {
    const int b    = blockIdx.x;
    const int tid  = threadIdx.x;
    const int q    = tid & 127;         // h-quad for gather
    const int p    = tid >> 7;          // parity class 0..7
    const int lane = tid & 63;
    const int wv   = tid >> 6;          // 0..15
    const bool st  = tid < HDIM;        // state-owning threads (wave-uniform)
    const int h    = tid;               // neuron id when st

    __shared__ unsigned long long wmask[8];
    __shared__ float4 part[8][128];                        // 16 KB
    __shared__ alignas(16) unsigned int slA[8][68];        // double-buffered
    __shared__ alignas(16) unsigned int slB[8][68];        //  8 parity lists
    unsigned int (*slO)[68] = slA;      // read list  (prev step's spikes)
    unsigned int (*slN)[68] = slB;      // build list (this step's spikes)

    const float kDvC  = 0.1f;    // DT*TAU_MEM_INV
    const float kSyn  = 0.2f;    // DT*TAU_SYN_INV
    const float kAda  = 0.002f;  // DT*TAU_ADA_INV

    float v = 0.f, cur = 0.f, a = 0.f;
    int   cnt = 0;
    const char* WQ = (const char*)WrecT + q * 16;   // + hp*2048 -> row hp, col 4q

    for (int t = 0; t < T_STEPS; ++t) {
        float ic = 0.f, i_dec = 0.f;
        bool  zk = false;
        unsigned long long m = 0;

        if (st) {
            ic = iin[((size_t)t * BATCH + b) * HDIM + h];
            // state update from carried state (uses rec folded into cur)
            float s = (0.0f - v) + 0.5f * expf((v - 1.0f) * 2.0f);
            s = s + cur;
            s = s - a;
            float v_dec = v + kDvC * s;
            i_dec = cur - kSyn * cur;
            float a_dec = a + kAda * (4.0f * v - a);
            zk = (v_dec - 1.0f) > 0.0f;

            m = __ballot(zk);
            if (lane == 0) {
                wmask[wv] = m;
                masksG[((size_t)t * BATCH + b) * 8 + wv] = m;
            }
            v = zk ? 0.0f : v_dec;
            a = zk ? (a_dec + 0.02f) : a_dec;
        }

        // ---- gather my parity class of PREVIOUS spikes (float4 per spike) ----
        float4 rs = {0.f, 0.f, 0.f, 0.f};
        {
            const int n  = (cnt + 7 - p) >> 3;      // entries in my sub-list
            const int ng = (n + 3) >> 2;            // padded groups of 4
            float4 b0[4], b1[4];
            auto ld4 = [&](int g, float4* d) {
                uint4 i0 = *(const uint4*)&slO[p][g << 2];
                d[0] = *(const float4*)(WQ + i0.x);
                d[1] = *(const float4*)(WQ + i0.y);
                d[2] = *(const float4*)(WQ + i0.z);
                d[3] = *(const float4*)(WQ + i0.w);
            };
            auto acc4 = [&](const float4* d) {
#pragma unroll
                for (int u = 0; u < 4; ++u) {
                    rs.x += d[u].x; rs.y += d[u].y; rs.z += d[u].z; rs.w += d[u].w;
                }
            };
            int g = 0;
            if (ng > 0) ld4(0, b0);
            while (g + 2 <= ng) {
                ld4(g + 1, b1);
                acc4(b0);
                if (g + 2 < ng) ld4(g + 2, b0);
                acc4(b1);
                g += 2;
            }
            if (g < ng) acc4(b0);
        }
        part[p][q] = rs;

        __syncthreads();   // B1: partials + wmask visible; slO fully consumed

        // everyone computes the new total (needed for next gather)
        int total = 0;
#pragma unroll
        for (int w = 0; w < 8; ++w) total += __popcll(wmask[w]);

        if (st) {
            // combine partials, ascending p (deterministic)
            float rec = 0.f;
#pragma unroll
            for (int pp = 0; pp < 8; ++pp)
                rec += ((const float*)&part[pp][h >> 2])[h & 3];
            cur = (i_dec + ic) + rec;

            // position of my spike among all (ascending h), scatter to sub-list
            if (zk) {
                int off = __popcll(m & ((1ull << lane) - 1ull));
#pragma unroll
                for (int w = 0; w < 8; ++w)
                    if (w < wv) off += __popcll(wmask[w]);
                slN[off & 7][off >> 3] = (unsigned int)h << 11;
            }
        } else if (tid < HDIM + 32) {
            // zero-row padding: sub-list s padded to multiple of 4
            int s  = (tid - HDIM) >> 2;
            int k  = (tid - HDIM) & 3;
            int ne = (total + 7 - s) >> 3;
            int padc = (4 - (ne & 3)) & 3;
            if (k < padc) slN[s][ne + k] = ZOFF;
        }
        cnt = total;

        __syncthreads();   // B2: new lists complete before next step's gather

        unsigned int (*tp)[68] = slO; slO = slN; slN = tp;
    }
}

// ---------------------------------------------------------------------------
// Readout from spike masks: y[t][b][o] = sum_{h' spiking} WoutT[h'][o] + b[o]
// ---------------------------------------------------------------------------
__global__ __launch_bounds__(256) void y_kernel(const unsigned long long* __restrict__ masks,
                                                const float* __restrict__ WoutT,
                                                const float* __restrict__ bout,
                                                float* __restrict__ y) {
    const int tid = threadIdx.x;
    const int p   = blockIdx.x * 8 + (tid >> 5);   // t*BATCH + b
    const int o   = tid & 31;
    const unsigned long long* mp = masks + (size_t)p * 8;
    float acc = 0.f;
#pragma unroll
    for (int w = 0; w < 8; ++w) {
        unsigned long long m = mp[w];
        const float* Wb = WoutT + (size_t)w * 64 * ODIM + o;
        while (m) {
            int j = __builtin_ctzll(m);
            acc += Wb[j * ODIM];
            m &= m - 1;
        }
    }
    y[(size_t)p * ODIM + o] = acc + bout[o];
}

// ---------------------------------------------------------------------------
// Exponential filter over t: 4096 independent (b,o) chains; 10-deep chunked
// prefetch hides L2 latency; 64-thread blocks spread over 64 CUs.
// ---------------------------------------------------------------------------
__global__ __launch_bounds__(64) void filter_kernel(const float* __restrict__ y,
                                                    const int* __restrict__ flag,
                                                    void* __restrict__ out) {
    const int p = blockIdx.x * 64 + threadIdx.x;   // b*ODIM + o
    const int fp32o = *flag;
    const float kf = 0.2231435511314f;   // DT*TAU_FILTER_INV
    float c0[10], c1[10];
#pragma unroll
    for (int u = 0; u < 10; ++u) c0[u] = y[(size_t)u * (BATCH * ODIM) + p];
    float o_state = 0.f;
    for (int base = 0; base < T_STEPS; base += 10) {
        if (base + 10 < T_STEPS) {
#pragma unroll
            for (int u = 0; u < 10; ++u)
                c1[u] = y[(size_t)(base + 10 + u) * (BATCH * ODIM) + p];
        }
#pragma unroll
        for (int u = 0; u < 10; ++u) {
            int t = base + u;
            float yt = c0[u];
            o_state = (t == 0) ? yt : (o_state + kf * (yt - o_state));
            size_t oi = (size_t)t * (BATCH * ODIM) + p;
            if (fp32o) ((float*)out)[oi] = o_state;
            else       ((__hip_bfloat16*)out)[oi] = __float2bfloat16(o_state);
        }
#pragma unroll
        for (int u = 0; u < 10; ++u) c0[u] = c1[u];
    }
}

// ---------------------------------------------------------------------------
extern "C" void kernel_launch(void* const* d_in, const int* in_sizes, int n_in,
                              void* d_out, int out_size, void* d_ws, size_t ws_size,
                              hipStream_t stream) {
    // select inputs by unique element count (robust to ordering)
    const void* x = d_in[0]; const void* Win = d_in[1]; const void* Wrec = d_in[2];
    const void* Wout = d_in[3]; const void* bout = d_in[4];
    for (int i = 0; i < n_in; ++i) {
        switch (in_sizes[i]) {
            case 8192000: x    = d_in[i]; break;
            case 65536:   Win  = d_in[i]; break;
            case 262144:  Wrec = d_in[i]; break;
            case 16384:   Wout = d_in[i]; break;
            case 32:      bout = d_in[i]; break;
            default: break;
        }
    }

    // workspace layout (bytes)
    const size_t OFF_FLAG  = 0;          // 4
    const size_t OFF_BOUT  = 256;        // 128
    const size_t OFF_WOUTT = 512;        // 65536
    const size_t OFF_WRECT = 66048;      // 513*512*4 = 1050624 (zero pad row)
    const size_t OFF_WINT  = 1116672;    // 262144
    const size_t OFF_MASK  = 1378816;    // 500*128*8*8 = 4096000
    const size_t OFF_IIN   = 5474816;    // 64000*512*4 = 131072000
    const size_t OFF_Y     = OFF_IIN;    // y (8.2 MB) aliases iin (dead after scan)
    const size_t REQUIRED  = OFF_IIN + (size_t)M_ROWS * HDIM * 4;  // 136546816
    if (ws_size < REQUIRED) return;  // diagnostic: output stays 0

    char* ws = (char*)d_ws;
    int*    flag   = (int*)(ws + OFF_FLAG);
    float*  bout32 = (float*)(ws + OFF_BOUT);
    float*  WoutT  = (float*)(ws + OFF_WOUTT);
    float*  WrecT  = (float*)(ws + OFF_WRECT);
    float*  WinT   = (float*)(ws + OFF_WINT);
    unsigned long long* masks = (unsigned long long*)(ws + OFF_MASK);
    float*  iin    = (float*)(ws + OFF_IIN);
    float*  y      = (float*)(ws + OFF_Y);

    hipLaunchKernelGGL(detect_kernel, dim3(1), dim3(256), 0, stream,
                       (const unsigned short*)x, flag);
    hipLaunchKernelGGL(prep_kernel, dim3((HDIM * HDIM + 255) / 256), dim3(256), 0, stream,
                       Wrec, Wout, bout, Win, flag, WrecT, WoutT, WinT, bout32);
    hipLaunchKernelGGL(iin_gemm, dim3(M_ROWS / 32), dim3(256), 0, stream,
                       x, WinT, flag, iin);
    hipLaunchKernelGGL(scan_kernel, dim3(BATCH), dim3(1024), 0, stream,
                       iin, WrecT, masks);
    hipLaunchKernelGGL(y_kernel, dim3(M_ROWS / 8), dim3(256), 0, stream,
                       masks, WoutT, bout32, y);
    hipLaunchKernelGGL(filter_kernel, dim3((BATCH * ODIM) / 64), dim3(64), 0, stream,
                       y, flag, d_out);
}

// Round 6
// 904.187 us; speedup vs baseline: 2.2196x; 1.0029x over previous
//
#include <hip/hip_runtime.h>
#include <hip/hip_bf16.h>
#include <cstdint>
#include <cstddef>

// Problem dims (fixed by reference)
#define T_STEPS 500
#define BATCH   128
#define FDIM    128
#define HDIM    512
#define ODIM    32
#define M_ROWS  (T_STEPS * BATCH)   // 64000
#define ZOFF    (512u << 11)        // zero-row byte offset, fp32 WrecT (2 KB rows)
#define ZOFFB   (512u << 10)        // zero-row byte offset, bf16 WrecTb (1 KB rows)

typedef __attribute__((ext_vector_type(8))) __bf16 bf16x8;
typedef __attribute__((ext_vector_type(4))) float  f32x4;

__device__ __forceinline__ float bfbits2f(unsigned short u) {
    union { unsigned int i; float f; } c; c.i = ((unsigned int)u) << 16; return c.f;
}
__device__ __forceinline__ float asf(unsigned int u) {
    union { unsigned int i; float f; } c; c.i = u; return c.f;
}
// LDS-only barrier: NO vmcnt drain (all cross-thread comms in the scan are LDS).
__device__ __forceinline__ void lds_barrier() {
    asm volatile("s_waitcnt lgkmcnt(0)" ::: "memory");
    __builtin_amdgcn_s_barrier();
}

// ---------------------------------------------------------------------------
// Dtype detect: flag=1 means fp32 inputs, flag=0 means bf16.
// ---------------------------------------------------------------------------
__global__ void detect_kernel(const unsigned short* __restrict__ xw, int* __restrict__ flag) {
    __shared__ int cnt;
    if (threadIdx.x == 0) cnt = 0;
    __syncthreads();
    unsigned short w = xw[threadIdx.x * 2];
    int e = (w >> 7) & 0xFF;
    if (e >= 170) atomicAdd(&cnt, 1);
    __syncthreads();
    if (threadIdx.x == 0) *flag = (cnt >= 8) ? 1 : 0;
}

// ---------------------------------------------------------------------------
// Prep. flag==0 (bf16): WrecTb[hp][h] = raw bf16 bits of W_rec[h][hp] (+zero row).
//       flag==1 (fp32): WrecT fp32 transpose (+zero row), WinT fp32 transpose.
// WoutT (fp32 [h][o]) and bout32 built either way. WrecTb aliases WrecT storage.
// ---------------------------------------------------------------------------
__global__ void prep_kernel(const void* __restrict__ Wrec,
                            const void* __restrict__ Wout,
                            const void* __restrict__ bout,
                            const void* __restrict__ Win,
                            const int* __restrict__ flag,
                            float* __restrict__ WrecT,
                            unsigned short* __restrict__ WrecTb,
                            float* __restrict__ WoutT,
                            float* __restrict__ WinT,
                            float* __restrict__ bout32) {
    const int fp32 = *flag;
    int idx = blockIdx.x * blockDim.x + threadIdx.x;
    if (fp32) {
        if (idx < HDIM * HDIM) {
            int h = idx / HDIM, hp = idx % HDIM;
            WrecT[hp * HDIM + h] = ((const float*)Wrec)[idx];
        }
        if (idx < HDIM) WrecT[HDIM * HDIM + idx] = 0.f;
        if (idx < HDIM * FDIM) {
            int h = idx / FDIM, f = idx % FDIM;
            WinT[f * HDIM + h] = ((const float*)Win)[idx];
        }
    } else {
        if (idx < HDIM * HDIM) {
            int h = idx / HDIM, hp = idx % HDIM;
            WrecTb[hp * HDIM + h] = ((const unsigned short*)Wrec)[idx];
        }
        if (idx < HDIM) WrecTb[HDIM * HDIM + idx] = 0;
    }
    if (idx < ODIM * HDIM) {
        int o = idx / HDIM, h = idx % HDIM;
        WoutT[h * ODIM + o] = fp32 ? ((const float*)Wout)[idx]
                                   : bfbits2f(((const unsigned short*)Wout)[idx]);
    }
    if (idx < ODIM)
        bout32[idx] = fp32 ? ((const float*)bout)[idx]
                           : bfbits2f(((const unsigned short*)bout)[idx]);
}

// ---------------------------------------------------------------------------
// i_in GEMM, MFMA path (flag==0, bf16 inputs). 16x16x32 bf16 MFMA.
// Block 256 thr = 4 waves; tile 64(m) x 64(n); K=128 in 4 steps.
// Layouts (HW-verified, guide m89/m91): A/B elem[m|n=lane&15][k=(lane>>4)*8+j];
// C/D: D[row=(lane>>4)*4+r][col=lane&15].
// ---------------------------------------------------------------------------
__global__ __launch_bounds__(256) void iin_gemm_mfma(const __hip_bfloat16* __restrict__ x,
                                                     const __hip_bfloat16* __restrict__ Win,
                                                     const int* __restrict__ flag,
                                                     float* __restrict__ iin) {
    if (*flag != 0) return;
    const int mt   = blockIdx.x;       // 0..999
    const int nt   = blockIdx.y;       // 0..7
    const int wave = threadIdx.x >> 6;
    const int lane = threadIdx.x & 63;
    const int l15  = lane & 15;
    const int quad = lane >> 4;
    const int m_base = mt * 64 + wave * 16;
    const int n_base = nt * 64;

    const __bf16* xb = reinterpret_cast<const __bf16*>(x);
    const __bf16* wb = reinterpret_cast<const __bf16*>(Win);

    f32x4 acc[4] = {{0.f,0.f,0.f,0.f},{0.f,0.f,0.f,0.f},{0.f,0.f,0.f,0.f},{0.f,0.f,0.f,0.f}};

#pragma unroll
    for (int kk = 0; kk < 4; ++kk) {
        const int k0 = kk * 32 + quad * 8;
        bf16x8 a = *reinterpret_cast<const bf16x8*>(xb + (size_t)(m_base + l15) * FDIM + k0);
#pragma unroll
        for (int nb = 0; nb < 4; ++nb) {
            bf16x8 bf = *reinterpret_cast<const bf16x8*>(wb + (size_t)(n_base + nb * 16 + l15) * FDIM + k0);
            acc[nb] = __builtin_amdgcn_mfma_f32_16x16x32_bf16(a, bf, acc[nb], 0, 0, 0);
        }
    }

#pragma unroll
    for (int nb = 0; nb < 4; ++nb)
#pragma unroll
        for (int r = 0; r < 4; ++r)
            iin[(size_t)(m_base + quad * 4 + r) * HDIM + n_base + nb * 16 + l15] = acc[nb][r];
}

// ---------------------------------------------------------------------------
// i_in GEMM, fp32 VALU fallback (flag==1).
// ---------------------------------------------------------------------------
__global__ __launch_bounds__(256) void iin_gemm_valu(const void* __restrict__ x,
                                                     const float* __restrict__ WinT,
                                                     const int* __restrict__ flag,
                                                     float* __restrict__ iin) {
    if (*flag != 1) return;
    const int tid  = threadIdx.x;
    const int m0   = blockIdx.x * 32;

    __shared__ float xs[32][FDIM];   // 16 KB

    for (int i = tid; i < 32 * FDIM; i += 256)
        xs[0][i] = ((const float*)x)[(size_t)m0 * FDIM + i];
    __syncthreads();

    float acc[32][2];
#pragma unroll
    for (int m = 0; m < 32; ++m) { acc[m][0] = 0.f; acc[m][1] = 0.f; }

#pragma unroll 4
    for (int k = 0; k < FDIM; ++k) {
        float w0 = WinT[(size_t)k * HDIM + tid];
        float w1 = WinT[(size_t)k * HDIM + 256 + tid];
#pragma unroll
        for (int m = 0; m < 32; ++m) {
            float xv = xs[m][k];
            acc[m][0] += xv * w0;
            acc[m][1] += xv * w1;
        }
    }

#pragma unroll
    for (int m = 0; m < 32; ++m) {
        iin[(size_t)(m0 + m) * HDIM + tid]       = acc[m][0];
        iin[(size_t)(m0 + m) * HDIM + 256 + tid] = acc[m][1];
    }
}

// ---------------------------------------------------------------------------
// Scan, bf16-weight path (flag==0). 128 WGs, 1024 threads.
// Gather: thread (q = tid&63 -> neuron octet 8q..8q+7, pc = tid>>6 -> one of
// 16 parity classes == its wave). Per spike: ONE 16B load = 8 bf16 weights
// (bit-exact upconvert). Sub-lists: 16 x uint32 byte offsets (hp<<10), padded
// to x4 with zero-row offset. Index reads are wave-uniform ds_read_b128.
// Partials in partA/partB [16][64] float4 (stride-16B contiguous, conflict-
// free). Raw LDS-only barriers (no vmcnt drain); iin prefetched 1 step ahead.
// ---------------------------------------------------------------------------
__global__ __launch_bounds__(1024) void scan_bf16(const float* __restrict__ iin,
                                                  const unsigned short* __restrict__ WrecTb,
                                                  const int* __restrict__ flag,
                                                  unsigned long long* __restrict__ masksG) {
    if (*flag != 0) return;
    const int b    = blockIdx.x;
    const int tid  = threadIdx.x;
    const int q    = tid & 63;          // neuron octet base h = 8q
    const int pc   = tid >> 6;          // parity class (== wave) 0..15
    const int lane = tid & 63;
    const int wv   = tid >> 6;
    const bool st  = tid < HDIM;        // state-owning threads
    const int h    = tid;

    __shared__ unsigned long long wmask[8];
    __shared__ float4 partA[16][64];                    // 4 KB
    __shared__ float4 partB[16][64];                    // 4 KB
    __shared__ alignas(16) unsigned int slA[16][36];    // double-buffered lists
    __shared__ alignas(16) unsigned int slB[16][36];
    unsigned int (*slO)[36] = slA;
    unsigned int (*slN)[36] = slB;

    float v = 0.f, cur = 0.f, a = 0.f;
    int   cnt = 0;
    const char* WQ = (const char*)WrecTb + q * 16;   // + (hp<<10) -> row hp, cols 8q..8q+7
    float ic_cur = st ? iin[(size_t)b * HDIM + h] : 0.f;   // t = 0

    for (int t = 0; t < T_STEPS; ++t) {
        // prefetch next step's feed-forward current (slack ~ full step)
        float ic_next = 0.f;
        if (st && (t + 1) < T_STEPS)
            ic_next = iin[((size_t)(t + 1) * BATCH + b) * HDIM + h];

        float i_dec = 0.f; bool zk = false; unsigned long long m = 0;
        if (st) {
            float s = (0.0f - v) + 0.5f * expf((v - 1.0f) * 2.0f);
            s = s + cur;
            s = s - a;
            float v_dec = v + 0.1f * s;
            i_dec = cur - 0.2f * cur;
            float a_dec = a + 0.002f * (4.0f * v - a);
            zk = (v_dec - 1.0f) > 0.0f;
            m = __ballot(zk);
            if (lane == 0) {
                wmask[wv] = m;
                masksG[((size_t)t * BATCH + b) * 8 + wv] = m;   // fire-and-forget
            }
            v = zk ? 0.0f : v_dec;
            a = zk ? (a_dec + 0.02f) : a_dec;
        }

        // ---- gather my parity class of PREVIOUS spikes (8 weights / load) ----
        float rs0=0.f,rs1=0.f,rs2=0.f,rs3=0.f,rs4=0.f,rs5=0.f,rs6=0.f,rs7=0.f;
        {
            const unsigned int* sl = slO[pc];
            const int n  = (cnt + 15 - pc) >> 4;   // my sub-list length
            const int ng = (n + 3) >> 2;           // padded groups of 4
            uint4 w0[4], w1[4];
            auto ldg = [&](int g, uint4* w) {
                uint4 ix = *(const uint4*)(sl + (g << 2));   // wave-uniform b128
                w[0] = *(const uint4*)(WQ + ix.x);
                w[1] = *(const uint4*)(WQ + ix.y);
                w[2] = *(const uint4*)(WQ + ix.z);
                w[3] = *(const uint4*)(WQ + ix.w);
            };
            auto accw = [&](const uint4* w) {
#pragma unroll
                for (int u = 0; u < 4; ++u) {
                    rs0 += asf(w[u].x << 16); rs1 += asf(w[u].x & 0xffff0000u);
                    rs2 += asf(w[u].y << 16); rs3 += asf(w[u].y & 0xffff0000u);
                    rs4 += asf(w[u].z << 16); rs5 += asf(w[u].z & 0xffff0000u);
                    rs6 += asf(w[u].w << 16); rs7 += asf(w[u].w & 0xffff0000u);
                }
            };
            int g = 0;
            if (ng > 0) ldg(0, w0);
            while (g + 2 <= ng) {
                ldg(g + 1, w1);
                accw(w0);
                if (g + 2 < ng) ldg(g + 2, w0);
                accw(w1);
                g += 2;
            }
            if (g < ng) accw(w0);
        }
        partA[pc][q] = (float4){rs0, rs1, rs2, rs3};
        partB[pc][q] = (float4){rs4, rs5, rs6, rs7};

        lds_barrier();   // B1: wmask + partials visible; slO fully consumed

        int total = 0;
#pragma unroll
        for (int w = 0; w < 8; ++w) total += __popcll(wmask[w]);

        if (st) {
            // combine partials, ascending pc (deterministic)
            float rec = 0.f;
            const int  qq = h >> 3, jj = h & 3;
            const bool hi = (h & 4) != 0;
#pragma unroll
            for (int pp = 0; pp < 16; ++pp) {
                const float* pa = (const float*)&partA[pp][qq];
                const float* pb = (const float*)&partB[pp][qq];
                rec += hi ? pb[jj] : pa[jj];
            }
            cur = (i_dec + ic_cur) + rec;

            if (zk) {
                int off = __popcll(m & ((1ull << lane) - 1ull));
#pragma unroll
                for (int w = 0; w < 8; ++w) if (w < wv) off += __popcll(wmask[w]);
                slN[off & 15][off >> 4] = (unsigned int)h << 10;
            }
        } else if (tid < HDIM + 64) {
            // zero-row padding: sub-list s5 padded to multiple of 4
            int s5 = (tid - HDIM) >> 2;
            int k  = (tid - HDIM) & 3;
            int ne = (total + 15 - s5) >> 4;
            int padc = (4 - (ne & 3)) & 3;
            if (k < padc) slN[s5][ne + k] = ZOFFB;
        }
        cnt = total;
        ic_cur = ic_next;

        lds_barrier();   // B2: new lists complete before next step's gather

        unsigned int (*tp)[36] = slO; slO = slN; slN = tp;
    }
}

// ---------------------------------------------------------------------------
// Scan, fp32 fallback (flag==1) — R5 version, known good.
// ---------------------------------------------------------------------------
__global__ __launch_bounds__(1024) void scan_f32(const float* __restrict__ iin,
                                                 const float* __restrict__ WrecT,
                                                 const int* __restrict__ flag,
                                                 unsigned long long* __restrict__ masksG) {
    if (*flag != 1) return;
    const int b    = blockIdx.x;
    const int tid  = threadIdx.x;
    const int q    = tid & 127;
    const int p    = tid >> 7;
    const int lane = tid & 63;
    const int wv   = tid >> 6;
    const bool st  = tid < HDIM;
    const int h    = tid;

    __shared__ unsigned long long wmask[8];
    __shared__ float4 part[8][128];
    __shared__ alignas(16) unsigned int slA[8][68];
    __shared__ alignas(16) unsigned int slB[8][68];
    unsigned int (*slO)[68] = slA;
    unsigned int (*slN)[68] = slB;

    float v = 0.f, cur = 0.f, a = 0.f;
    int   cnt = 0;
    const char* WQ = (const char*)WrecT + q * 16;

    for (int t = 0; t < T_STEPS; ++t) {
        float ic = 0.f, i_dec = 0.f;
        bool  zk = false;
        unsigned long long m = 0;

        if (st) {
            ic = iin[((size_t)t * BATCH + b) * HDIM + h];
            float s = (0.0f - v) + 0.5f * expf((v - 1.0f) * 2.0f);
            s = s + cur;
            s = s - a;
            float v_dec = v + 0.1f * s;
            i_dec = cur - 0.2f * cur;
            float a_dec = a + 0.002f * (4.0f * v - a);
            zk = (v_dec - 1.0f) > 0.0f;
            m = __ballot(zk);
            if (lane == 0) {
                wmask[wv] = m;
                masksG[((size_t)t * BATCH + b) * 8 + wv] = m;
            }
            v = zk ? 0.0f : v_dec;
            a = zk ? (a_dec + 0.02f) : a_dec;
        }

        float4 rs = {0.f, 0.f, 0.f, 0.f};
        {
            const int n  = (cnt + 7 - p) >> 3;
            const int ng = (n + 3) >> 2;
            float4 b0[4], b1[4];
            auto ld4 = [&](int g, float4* d) {
                uint4 i0 = *(const uint4*)&slO[p][g << 2];
                d[0] = *(const float4*)(WQ + i0.x);
                d[1] = *(const float4*)(WQ + i0.y);
                d[2] = *(const float4*)(WQ + i0.z);
                d[3] = *(const float4*)(WQ + i0.w);
            };
            auto acc4 = [&](const float4* d) {
#pragma unroll
                for (int u = 0; u < 4; ++u) {
                    rs.x += d[u].x; rs.y += d[u].y; rs.z += d[u].z; rs.w += d[u].w;
                }
            };
            int g = 0;
            if (ng > 0) ld4(0, b0);
            while (g + 2 <= ng) {
                ld4(g + 1, b1);
                acc4(b0);
                if (g + 2 < ng) ld4(g + 2, b0);
                acc4(b1);
                g += 2;
            }
            if (g < ng) acc4(b0);
        }
        part[p][q] = rs;

        __syncthreads();

        int total = 0;
#pragma unroll
        for (int w = 0; w < 8; ++w) total += __popcll(wmask[w]);

        if (st) {
            float rec = 0.f;
#pragma unroll
            for (int pp = 0; pp < 8; ++pp)
                rec += ((const float*)&part[pp][h >> 2])[h & 3];
            cur = (i_dec + ic) + rec;
            if (zk) {
                int off = __popcll(m & ((1ull << lane) - 1ull));
#pragma unroll
                for (int w = 0; w < 8; ++w) if (w < wv) off += __popcll(wmask[w]);
                slN[off & 7][off >> 3] = (unsigned int)h << 11;
            }
        } else if (tid < HDIM + 32) {
            int s5 = (tid - HDIM) >> 2;
            int k  = (tid - HDIM) & 3;
            int ne = (total + 7 - s5) >> 3;
            int padc = (4 - (ne & 3)) & 3;
            if (k < padc) slN[s5][ne + k] = ZOFF;
        }
        cnt = total;

        __syncthreads();

        unsigned int (*tp)[68] = slO; slO = slN; slN = tp;
    }
}

// ---------------------------------------------------------------------------
// Readout from spike masks: y[t][b][o] = sum_{h' spiking} WoutT[h'][o] + b[o]
// ---------------------------------------------------------------------------
__global__ __launch_bounds__(256) void y_kernel(const unsigned long long* __restrict__ masks,
                                                const float* __restrict__ WoutT,
                                                const float* __restrict__ bout,
                                                float* __restrict__ y) {
    const int tid = threadIdx.x;
    const int p   = blockIdx.x * 8 + (tid >> 5);   // t*BATCH + b
    const int o   = tid & 31;
    const unsigned long long* mp = masks + (size_t)p * 8;
    float acc = 0.f;
#pragma unroll
    for (int w = 0; w < 8; ++w) {
        unsigned long long m = mp[w];
        const float* Wb = WoutT + (size_t)w * 64 * ODIM + o;
        while (m) {
            int j = __builtin_ctzll(m);
            acc += Wb[j * ODIM];
            m &= m - 1;
        }
    }
    y[(size_t)p * ODIM + o] = acc + bout[o];
}

// ---------------------------------------------------------------------------
// Exponential filter over t: 4096 independent (b,o) chains; chunked prefetch.
// ---------------------------------------------------------------------------
__global__ __launch_bounds__(64) void filter_kernel(const float* __restrict__ y,
                                                    const int* __restrict__ flag,
                                                    void* __restrict__ out) {
    const int p = blockIdx.x * 64 + threadIdx.x;   // b*ODIM + o
    const int fp32o = *flag;
    const float kf = 0.2231435511314f;   // DT*TAU_FILTER_INV
    float c0[10], c1[10];
#pragma unroll
    for (int u = 0; u < 10; ++u) c0[u] = y[(size_t)u * (BATCH * ODIM) + p];
    float o_state = 0.f;
    for (int base = 0; base < T_STEPS; base += 10) {
        if (base + 10 < T_STEPS) {
#pragma unroll
            for (int u = 0; u < 10; ++u)
                c1[u] = y[(size_t)(base + 10 + u) * (BATCH * ODIM) + p];
        }
#pragma unroll
        for (int u = 0; u < 10; ++u) {
            int t = base + u;
            float yt = c0[u];
            o_state = (t == 0) ? yt : (o_state + kf * (yt - o_state));
            size_t oi = (size_t)t * (BATCH * ODIM) + p;
            if (fp32o) ((float*)out)[oi] = o_state;
            else       ((__hip_bfloat16*)out)[oi] = __float2bfloat16(o_state);
        }
#pragma unroll
        for (int u = 0; u < 10; ++u) c0[u] = c1[u];
    }
}

// ---------------------------------------------------------------------------
extern "C" void kernel_launch(void* const* d_in, const int* in_sizes, int n_in,
                              void* d_out, int out_size, void* d_ws, size_t ws_size,
                              hipStream_t stream) {
    // select inputs by unique element count (robust to ordering)
    const void* x = d_in[0]; const void* Win = d_in[1]; const void* Wrec = d_in[2];
    const void* Wout = d_in[3]; const void* bout = d_in[4];
    for (int i = 0; i < n_in; ++i) {
        switch (in_sizes[i]) {
            case 8192000: x    = d_in[i]; break;
            case 65536:   Win  = d_in[i]; break;
            case 262144:  Wrec = d_in[i]; break;
            case 16384:   Wout = d_in[i]; break;
            case 32:      bout = d_in[i]; break;
            default: break;
        }
    }

    // workspace layout (bytes) — WrecTb (bf16) aliases WrecT (fp32) storage
    const size_t OFF_FLAG  = 0;          // 4
    const size_t OFF_BOUT  = 256;        // 128
    const size_t OFF_WOUTT = 512;        // 65536
    const size_t OFF_WRECT = 66048;      // 513*512*4 = 1050624 (or 513*512*2 bf16)
    const size_t OFF_WINT  = 1116672;    // 262144
    const size_t OFF_MASK  = 1378816;    // 500*128*8*8 = 4096000
    const size_t OFF_IIN   = 5474816;    // 64000*512*4 = 131072000
    const size_t OFF_Y     = OFF_IIN;    // y (8.2 MB) aliases iin (dead after scan)
    const size_t REQUIRED  = OFF_IIN + (size_t)M_ROWS * HDIM * 4;  // 136546816
    if (ws_size < REQUIRED) return;  // diagnostic: output stays 0

    char* ws = (char*)d_ws;
    int*            flag   = (int*)(ws + OFF_FLAG);
    float*          bout32 = (float*)(ws + OFF_BOUT);
    float*          WoutT  = (float*)(ws + OFF_WOUTT);
    float*          WrecT  = (float*)(ws + OFF_WRECT);
    unsigned short* WrecTb = (unsigned short*)(ws + OFF_WRECT);
    float*          WinT   = (float*)(ws + OFF_WINT);
    unsigned long long* masks = (unsigned long long*)(ws + OFF_MASK);
    float*          iin    = (float*)(ws + OFF_IIN);
    float*          y      = (float*)(ws + OFF_Y);

    hipLaunchKernelGGL(detect_kernel, dim3(1), dim3(256), 0, stream,
                       (const unsigned short*)x, flag);
    hipLaunchKernelGGL(prep_kernel, dim3((HDIM * HDIM + 255) / 256), dim3(256), 0, stream,
                       Wrec, Wout, bout, Win, flag, WrecT, WrecTb, WoutT, WinT, bout32);
    hipLaunchKernelGGL(iin_gemm_mfma, dim3(M_ROWS / 64, HDIM / 64), dim3(256), 0, stream,
                       (const __hip_bfloat16*)x, (const __hip_bfloat16*)Win, flag, iin);
    hipLaunchKernelGGL(iin_gemm_valu, dim3(M_ROWS / 32), dim3(256), 0, stream,
                       x, WinT, flag, iin);
    hipLaunchKernelGGL(scan_bf16, dim3(BATCH), dim3(1024), 0, stream,
                       iin, WrecTb, flag, masks);
    hipLaunchKernelGGL(scan_f32, dim3(BATCH), dim3(1024), 0, stream,
                       iin, WrecT, flag, masks);
    hipLaunchKernelGGL(y_kernel, dim3(M_ROWS / 8), dim3(256), 0, stream,
                       masks, WoutT, bout32, y);
    hipLaunchKernelGGL(filter_kernel, dim3((BATCH * ODIM) / 64), dim3(64), 0, stream,
                       y, flag, d_out);
}